// Round 7
// baseline (137.191 us; speedup 1.0000x reference)
//
#include <hip/hip_runtime.h>
#include <hip/hip_fp16.h>

// GCN-style symmetric-normalized CSR aggregation.
// out[d][f] = sum_e feat[col_idx[e]][f] * rsqrt(deg[d]*deg[col_idx[e]])
//
// Round-13 theory: six rounds pin the cost to TOTAL DISTINCT 64B LINES
// requested (invariant ~0.114 lines/cyc/CU service rate; schedule,
// occupancy, balance, and latency all exonerated). fp16 rows = 128B =
// 2 lines/edge = 3.2M lines = ~45us. Halve the lines:
//   int8 per-row-scaled table: row = 64 x 1B = ONE 64B line per edge,
//   scale[row] = max|feat*rsqrt(deg)| / 127 in a 400KB L2-hot array.
//   Gather: 4 lanes x 16B per edge -> 16 edges per instruction.
//   Unpack: sign-extend + cvt + fma(scale). Accuracy ~0.4% relative
//   (strictly better than fp8), absmax expected ~2-4x fp16's 0.0156.

typedef float    v4f __attribute__((ext_vector_type(4)));
typedef unsigned v4u __attribute__((ext_vector_type(4)));

// ---- pass 1: fold rsqrt(deg), per-row int8 quantize (+ zero row) ----------
// One 64-lane wave per node row: lane f handles feature f.
__global__ __launch_bounds__(256) void conv_q8(
    const float* __restrict__ feat, const float* __restrict__ deg,
    char* __restrict__ qtab, float* __restrict__ scales, int n_nodes)
{
    const int wid  = (blockIdx.x * blockDim.x + threadIdx.x) >> 6;
    const int lane = threadIdx.x & 63;
    if (wid > n_nodes) return;
    if (wid == n_nodes) {                       // zero row
        qtab[(size_t)wid * 64 + lane] = 0;
        if (lane == 0) scales[wid] = 0.f;
        return;
    }
    const float w = rsqrtf(deg[wid]);           // deg clamped >= 1 by setup
    const float v = feat[(size_t)wid * 64 + lane] * w;
    float a = fabsf(v);
#pragma unroll
    for (int m = 1; m <= 32; m <<= 1) a = fmaxf(a, __shfl_xor(a, m));
    const float inv = (a > 0.f) ? 127.f / a : 0.f;
    int q = (int)rintf(v * inv);
    q = max(-127, min(127, q));
    qtab[(size_t)wid * 64 + lane] = (char)q;
    if (lane == 0) scales[wid] = (a > 0.f) ? a / 127.f : 0.f;
}

// ---- pass 2: persistent gather, 2 rows/wave, 1 line per edge --------------
// lane = [half(b5) | slot(b4..b2) | k(b1..b0)]: 8 edge-slots x 4 k-lanes
// per half; lane k loads bytes [16k,16k+16) = features [16k,16k+16).
__global__ __launch_bounds__(256, 4) void gcn_q8(
    const int* __restrict__ row_ptr,
    const int* __restrict__ col_idx,
    const char* __restrict__ qtab,       // int8, weight-folded, 64B rows
    const float* __restrict__ scales,    // per-row dequant scale
    const float* __restrict__ deg,
    float* __restrict__ out,
    int n_nodes, int n_edges)
{
    const int lane = threadIdx.x & 63;
    const int half = lane >> 5;
    const int slot = (lane >> 2) & 7;
    const int k    = lane & 3;
    const int kb   = k << 4;
    const int Em1  = n_edges - 1;
    const int zrow = n_nodes;

    const int wid = (blockIdx.x * blockDim.x + threadIdx.x) >> 6;
    const int nw  = (gridDim.x * blockDim.x) >> 6;
    const int npairs = (n_nodes + 1) >> 1;
    if (wid >= npairs) return;

    int pair  = wid;
    int row   = min(pair * 2 + half, n_nodes - 1);
    int start = row_ptr[row];
    int end   = row_ptr[row + 1];
    float dcur = deg[row];

    for (;;) {
        // prefetch next pair's bounds + deg (hidden under the gather)
        const int npair  = pair + nw;
        const int nrow   = min(min(npair, npairs - 1) * 2 + half, n_nodes - 1);
        const int nstart = row_ptr[nrow];
        const int nend   = row_ptr[nrow + 1];
        const float ndeg = deg[nrow];

        const int deg_r = end - start;
        const int degM  = max(deg_r, __shfl_xor(deg_r, 32));

        float acc[16];
#pragma unroll
        for (int i = 0; i < 16; ++i) acc[i] = 0.f;

        for (int base = 0; base < degM; base += 32) {
            const int eb0 = start + base + slot;
            int s[4];
#pragma unroll
            for (int u = 0; u < 4; ++u) {
                const int e = eb0 + 8 * u;
                const int c = col_idx[min(e, Em1)];
                s[u] = (e < end) ? c : zrow;   // tail -> zero row (scale 0)
            }
            // issue all 4 row-gathers + 4 scale loads before consuming
            v4u q[4];
#pragma unroll
            for (int u = 0; u < 4; ++u)
                q[u] = *reinterpret_cast<const v4u*>(
                    qtab + (((unsigned)s[u]) << 6) + kb);
            float sc[4];
#pragma unroll
            for (int u = 0; u < 4; ++u) sc[u] = scales[s[u]];
            __builtin_amdgcn_sched_barrier(0);
#pragma unroll
            for (int u = 0; u < 4; ++u) {
#pragma unroll
                for (int p = 0; p < 4; ++p) {
                    const unsigned d = q[u][p];
                    const float f0 = (float)((int)(d << 24) >> 24);
                    const float f1 = (float)((int)(d << 16) >> 24);
                    const float f2 = (float)((int)(d <<  8) >> 24);
                    const float f3 = (float)((int)d >> 24);
                    acc[4 * p + 0] = fmaf(sc[u], f0, acc[4 * p + 0]);
                    acc[4 * p + 1] = fmaf(sc[u], f1, acc[4 * p + 1]);
                    acc[4 * p + 2] = fmaf(sc[u], f2, acc[4 * p + 2]);
                    acc[4 * p + 3] = fmaf(sc[u], f3, acc[4 * p + 3]);
                }
            }
        }

        // reduce across the 8 slots of each half (lane bits 2,3,4)
#pragma unroll
        for (int m = 4; m <= 16; m <<= 1) {
#pragma unroll
            for (int i = 0; i < 16; ++i) acc[i] += __shfl_xor(acc[i], m);
        }

        if (slot == 0) {                   // 4 lanes per half, k = 0..3
            const float dinv = rsqrtf(dcur);
            char* po = (char*)out + (((unsigned)row) << 8) + (k << 6);
#pragma unroll
            for (int p = 0; p < 4; ++p) {
                v4f v = {acc[4 * p] * dinv, acc[4 * p + 1] * dinv,
                         acc[4 * p + 2] * dinv, acc[4 * p + 3] * dinv};
                __builtin_nontemporal_store(v, reinterpret_cast<v4f*>(po + 16 * p));
            }
        }

        if (npair >= npairs) break;
        pair = npair; row = nrow; start = nstart; end = nend; dcur = ndeg;
    }
}

// ---------------- fallback: fp32 gather (round-3 kernel) --------------------
__global__ __launch_bounds__(256) void gcn_csr_agg_f(
    const int* __restrict__ row_ptr,
    const int* __restrict__ col_idx,
    const float* __restrict__ feat,
    const float* __restrict__ deg,
    float* __restrict__ out,
    int n_nodes)
{
    const int gtid = blockIdx.x * blockDim.x + threadIdx.x;
    const int row  = gtid >> 6;
    if (row >= n_nodes) return;
    const int lane = threadIdx.x & 63;
    const int sub  = lane >> 4;
    const int fbyte = (lane & 15) << 4;

    const int start = row_ptr[row];
    const int end   = row_ptr[row + 1];
    const int last  = end - 1;
    const float dinv = rsqrtf(deg[row]);
    const char* fbase = (const char*)feat;

    v4f acc = {0.f, 0.f, 0.f, 0.f};

    for (int eb = start; eb < end; eb += 16) {
        int e[4]; int s[4]; float d[4]; v4f f[4];
#pragma unroll
        for (int u = 0; u < 4; ++u) {
            e[u] = eb + sub + 4 * u;
            const int c = min(e[u], last);
            s[u] = col_idx[c];
        }
#pragma unroll
        for (int u = 0; u < 4; ++u) {
            d[u] = deg[s[u]];
            const unsigned off = ((unsigned)s[u] << 8) + fbyte;
            f[u] = *reinterpret_cast<const v4f*>(fbase + off);
        }
#pragma unroll
        for (int u = 0; u < 4; ++u) {
            const float w = (e[u] <= last) ? dinv * rsqrtf(d[u]) : 0.f;
            acc += w * f[u];
        }
    }

    acc.x += __shfl_xor(acc.x, 16); acc.y += __shfl_xor(acc.y, 16);
    acc.z += __shfl_xor(acc.z, 16); acc.w += __shfl_xor(acc.w, 16);
    acc.x += __shfl_xor(acc.x, 32); acc.y += __shfl_xor(acc.y, 32);
    acc.z += __shfl_xor(acc.z, 32); acc.w += __shfl_xor(acc.w, 32);

    if (sub == 0) {
        v4f* po = reinterpret_cast<v4f*>((char*)out + ((unsigned)row << 8) + fbyte);
        __builtin_nontemporal_store(acc, po);
    }
}

extern "C" void kernel_launch(void* const* d_in, const int* in_sizes, int n_in,
                              void* d_out, int out_size, void* d_ws, size_t ws_size,
                              hipStream_t stream) {
    const int*   row_ptr = (const int*)d_in[0];
    const int*   col_idx = (const int*)d_in[1];
    const float* feat    = (const float*)d_in[2];
    const float* deg     = (const float*)d_in[3];
    float*       out     = (float*)d_out;

    const int n_nodes = in_sizes[0] - 1;
    const int n_edges = in_sizes[1];
    const size_t q_bytes  = ((size_t)n_nodes + 1) * 64;  // int8 table
    const size_t s_bytes  = ((size_t)n_nodes + 1) * 4;   // scales
    const int block = 256;

    if (ws_size >= q_bytes + s_bytes && n_edges > 0) {
        char*  qtab   = (char*)d_ws;
        float* scales = (float*)((char*)d_ws + q_bytes);

        const long long cth = (long long)(n_nodes + 1) * 64;
        const int cgrid = (int)((cth + block - 1) / block);
        conv_q8<<<cgrid, block, 0, stream>>>(feat, deg, qtab, scales, n_nodes);

        const int npairs = (n_nodes + 1) >> 1;
        const int max_blocks = 2048;                  // persistent grid
        long long need_blocks = ((long long)npairs * 64 + block - 1) / block;
        const int grid = (int)(need_blocks < max_blocks ? need_blocks : max_blocks);
        gcn_q8<<<grid, block, 0, stream>>>(
            row_ptr, col_idx, qtab, scales, deg, out, n_nodes, n_edges);
    } else {
        const long long threads = (long long)n_nodes * 64;
        const int grid  = (int)((threads + block - 1) / block);
        gcn_csr_agg_f<<<grid, block, 0, stream>>>(
            row_ptr, col_idx, feat, deg, out, n_nodes);
    }
}